// Round 6
// baseline (335.726 us; speedup 1.0000x reference)
//
#include <hip/hip_runtime.h>
#include <hip/hip_bf16.h>
#include <math.h>

#define BB 16
#define CC 512
#define HWN 4096
#define KK 4
#define DD 32
#define KD 128
#define NPIX 64

typedef __attribute__((ext_vector_type(8))) short short8;
typedef __attribute__((ext_vector_type(4))) float f32x4;

// ws float offsets
#define WS_Y     0         // [B*C]            8192 f
#define WS_WGT   8192      // [B*K]            64 f
#define WS_BIAS2 8256      // [B*C]            8192 f
#define WS_W1B   16448     // 65536 ushort  = 32768 f
#define WS_W2B   49216     // 65536 ushort  = 32768 f
#define WS_XP    81984     // 33554432 ushort = 16777216 f (packed bf16 x, 67 MB)

__device__ inline unsigned short f2bf(float f) {
    unsigned u = __builtin_bit_cast(unsigned, f);
    unsigned r = (u + 0x7FFFu + ((u >> 16) & 1u)) >> 16;
    return (unsigned short)r;
}

// ---------------- kernel 1: y[b,c] = mean_{hw} x[b,c,hw] ----------------
__global__ __launch_bounds__(256) void mean_kernel(const float* __restrict__ x,
                                                   float* __restrict__ y) {
    int wave = threadIdx.x >> 6;
    int lane = threadIdx.x & 63;
    int row  = blockIdx.x * 4 + wave;
    const float4* xr = (const float4*)(x + (size_t)row * HWN);
    float s = 0.f;
    #pragma unroll
    for (int i = 0; i < 16; i++) {
        float4 v = xr[i * 64 + lane];
        s += (v.x + v.y) + (v.z + v.w);
    }
    #pragma unroll
    for (int off = 32; off > 0; off >>= 1)
        s += __shfl_down(s, off, 64);
    if (lane == 0) y[row] = s * (1.0f / HWN);
}

// ---- kernel 1b: pack x -> xp bf16, B-frag layout [b][ks][pix][32 csub] ----
// grid (HW/256, C/32, B), 256 threads; x is L3-resident after mean_kernel.
__global__ __launch_bounds__(256) void pack_kernel(const float* __restrict__ x,
                                                   unsigned short* __restrict__ xp) {
    const int b = blockIdx.z, ks = blockIdx.y;
    const int pix = blockIdx.x * 256 + threadIdx.x;
    const float* xc = x + (size_t)(b * CC + ks * 32) * HWN + pix;
    unsigned u[16];
    #pragma unroll
    for (int c2 = 0; c2 < 16; c2++) {
        float v0 = xc[(size_t)(2 * c2) * HWN];
        float v1 = xc[(size_t)(2 * c2 + 1) * HWN];
        u[c2] = (unsigned)f2bf(v0) | ((unsigned)f2bf(v1) << 16);
    }
    uint4* dst = (uint4*)(xp + ((size_t)(b * 16 + ks) * HWN + pix) * 32);
    #pragma unroll
    for (int q = 0; q < 4; q++) {
        uint4 v; v.x = u[q*4]; v.y = u[q*4+1]; v.z = u[q*4+2]; v.w = u[q*4+3];
        dst[q] = v;
    }
}

// ---------------- kernel 2: routing softmax -> wgt[b,k] ----------------
__global__ __launch_bounds__(64) void route_kernel(const float* __restrict__ y,
                                                   const float* __restrict__ fc_w,
                                                   const float* __restrict__ fc_b,
                                                   float* __restrict__ wgt) {
    __shared__ float logits[BB][KK];
    int t = threadIdx.x;
    int b = t >> 2, k = t & 3;
    const float4* y4 = (const float4*)(y + b * CC);
    const float4* f4 = (const float4*)(fc_w + k * CC);
    float s = fc_b[k];
    for (int i = 0; i < CC / 4; i++) {
        float4 a = y4[i], w = f4[i];
        s += a.x * w.x + a.y * w.y + a.z * w.z + a.w * w.w;
    }
    logits[b][k] = s;
    __syncthreads();
    if (k == 0) {
        float m = logits[b][0];
        #pragma unroll
        for (int j = 1; j < KK; j++) m = fmaxf(m, logits[b][j]);
        float e[KK], sum = 0.f;
        #pragma unroll
        for (int j = 0; j < KK; j++) { e[j] = __expf(logits[b][j] - m); sum += e[j]; }
        float inv = 1.f / sum;
        #pragma unroll
        for (int j = 0; j < KK; j++) wgt[b * KK + j] = e[j] * inv;
    }
}

// ---- kernel 3: pack W1/W2t into MFMA-fragment-ordered bf16; bias2 ----
__global__ __launch_bounds__(256) void prep_kernel(const float* __restrict__ w1,
                                                   const float* __restrict__ w2,
                                                   const float* __restrict__ b2,
                                                   const float* __restrict__ wgt,
                                                   unsigned short* __restrict__ w1b,
                                                   unsigned short* __restrict__ w2b,
                                                   float* __restrict__ bias2) {
    int tid = blockIdx.x * 256 + threadIdx.x;
    int n   = gridDim.x * 256;
    for (int idx = tid; idx < CC * KD; idx += n) {
        int f = idx >> 9, rem = idx & 511;
        int l = rem >> 3, i = rem & 7;
        int ks = f >> 3, m = f & 7;
        int kd = m * 16 + (l & 15);
        int c  = ks * 32 + (l >> 4) * 8 + i;
        w1b[idx] = f2bf(w1[kd * CC + c]);            // w1 is [KD][C]
    }
    for (int idx = tid; idx < CC * KD; idx += n) {
        int f = idx >> 9, rem = idx & 511;
        int l = rem >> 3, i = rem & 7;
        int mc = f >> 2, kk = f & 3;
        int c = mc * 16 + (l & 15);
        int d = (l >> 4) * 8 + i;
        w2b[idx] = f2bf(w2[(kk * CC + c) * DD + d]); // w2 is [K][C][D]
    }
    for (int idx = tid; idx < BB * CC; idx += n) {
        int bb = idx >> 9, c = idx & 511;
        float s = 0.f;
        #pragma unroll
        for (int k = 0; k < KK; k++) s += wgt[bb * KK + k] * b2[k * CC + c];
        bias2[idx] = s;
    }
}

// ---------------- kernel 4: fused MFMA MLP, split-K, 8 waves ----------------
// grid (HW/64, B), block 512 = 8 waves. wave wv: pg = wv&3 (16-pixel group),
// kh = wv>>2 (C-half). GEMM1 B-frags come pre-packed from xp (coalesced
// short8 loads). Upper waves publish fp32 partials to LDS; lower waves
// reduce + relu + wgt -> bf16 hid. GEMM2: 64 output channels per wave.
__global__ __launch_bounds__(512, 4) void main_kernel(const float* __restrict__ x,
                                                      const unsigned short* __restrict__ xp,
                                                      const unsigned short* __restrict__ w1b,
                                                      const float* __restrict__ b1,
                                                      const unsigned short* __restrict__ w2b,
                                                      const float* __restrict__ wgt,
                                                      const float* __restrict__ bias2,
                                                      float* __restrict__ out) {
    __shared__ char lds[4 * 8192];   // [pg][8 KB]

    const int b       = blockIdx.y;
    const int pixbase = blockIdx.x * NPIX;
    const int tid = threadIdx.x;
    const int wv  = tid >> 6;
    const int l   = tid & 63;
    const int l15 = l & 15, lg = l >> 4;
    const int pg  = wv & 3;
    const int kh  = wv >> 2;

    const short8* w1f = (const short8*)w1b;
    const short8* w2f = (const short8*)w2b;
    const short8* xps = (const short8*)xp;

    // ===== GEMM1 partial: ks in [kh*8, kh*8+8), B-frags direct from xp =====
    f32x4 acc1[8];
    #pragma unroll
    for (int m = 0; m < 8; m++) acc1[m] = (f32x4)0.f;

    const int mypix = pixbase + pg * 16 + l15;
    const size_t xbase = ((size_t)(b * 16 + kh * 8) * HWN + mypix) * 4 + lg;

    short8 bfr[8];
    #pragma unroll
    for (int ks8 = 0; ks8 < 8; ks8++)
        bfr[ks8] = xps[xbase + (size_t)ks8 * HWN * 4];

    #pragma unroll
    for (int ks8 = 0; ks8 < 8; ks8++) {
        const int ks = kh * 8 + ks8;
        #pragma unroll
        for (int m = 0; m < 8; m++) {
            short8 af = w1f[(ks * 8 + m) * 64 + l];
            acc1[m] = __builtin_amdgcn_mfma_f32_16x16x32_bf16(af, bfr[ks8], acc1[m], 0, 0, 0);
        }
    }

    // ===== upper waves publish fp32 partials (contiguous 1 KB/wave) =====
    if (kh == 1) {
        char* base = lds + pg * 8192 + lg * 256 + l15 * 16;
        #pragma unroll
        for (int m = 0; m < 8; m++)
            *(f32x4*)(base + m * 1024) = acc1[m];
    }
    __syncthreads();

    // ===== lower waves: reduce + relu + bias + wgt -> bf16 hid =====
    if (kh == 0) {
        const char* pbase = lds + pg * 8192 + lg * 256 + l15 * 16;
        #pragma unroll
        for (int half = 0; half < 2; half++) {
            f32x4 pp[4];
            #pragma unroll
            for (int m4 = 0; m4 < 4; m4++)
                pp[m4] = *(const f32x4*)(pbase + (half * 4 + m4) * 1024);
            #pragma unroll
            for (int m4 = 0; m4 < 4; m4++) {
                const int m = half * 4 + m4;
                f32x4 bv = *(const f32x4*)(b1 + m * 16 + lg * 4);
                float wk = wgt[b * KK + (m >> 1)];
                f32x4 s = acc1[m] + pp[m4];
                unsigned short h[4];
                #pragma unroll
                for (int r = 0; r < 4; r++) {
                    float t = fmaxf(s[r] + bv[r], 0.f) * wk;
                    h[r] = f2bf(t);
                }
                unsigned lo = (unsigned)h[0] | ((unsigned)h[1] << 16);
                unsigned hi = (unsigned)h[2] | ((unsigned)h[3] << 16);
                int byteoff = pg * 8192 + l15 * 256 + (m * 16 + lg * 4) * 2;
                byteoff ^= (l15 & 7) << 4;
                uint2 v; v.x = lo; v.y = hi;
                *(uint2*)(lds + byteoff) = v;
            }
        }
    }
    __syncthreads();

    // ===== GEMM2: 64 channels per wave, sigmoid gate, multiply, store =====
    const float* bb2 = bias2 + b * CC;
    #pragma unroll
    for (int mblk = 0; mblk < 4; mblk++) {
        f32x4 acc[4];
        #pragma unroll
        for (int nb = 0; nb < 4; nb++) acc[nb] = (f32x4)0.f;
        #pragma unroll
        for (int kk = 0; kk < 4; kk++) {
            short8 af = w2f[((wv * 4 + mblk) * 4 + kk) * 64 + l];
            #pragma unroll
            for (int nb = 0; nb < 4; nb++) {
                int byteoff = nb * 8192 + l15 * 256 + kk * 64 + lg * 16;
                byteoff ^= (l15 & 7) << 4;
                short8 bf = *(const short8*)(lds + byteoff);
                acc[nb] = __builtin_amdgcn_mfma_f32_16x16x32_bf16(af, bf, acc[nb], 0, 0, 0);
            }
        }
        const int cb = wv * 64 + mblk * 16 + lg * 4;
        f32x4 b2v = *(const f32x4*)(bb2 + cb);
        #pragma unroll
        for (int nb = 0; nb < 4; nb++) {
            int pix = pixbase + nb * 16 + l15;
            #pragma unroll
            for (int r = 0; r < 4; r++) {
                size_t off = ((size_t)b * CC + cb + r) * HWN + pix;
                float s = acc[nb][r] + b2v[r];
                float attn = __builtin_amdgcn_rcpf(1.f + __expf(-s));
                __builtin_nontemporal_store(x[off] * attn, &out[off]);
            }
        }
    }
}

extern "C" void kernel_launch(void* const* d_in, const int* in_sizes, int n_in,
                              void* d_out, int out_size, void* d_ws, size_t ws_size,
                              hipStream_t stream) {
    const float* x    = (const float*)d_in[0];
    const float* fc_w = (const float*)d_in[1];
    const float* fc_b = (const float*)d_in[2];
    const float* w1   = (const float*)d_in[3];
    const float* b1   = (const float*)d_in[4];
    const float* w2   = (const float*)d_in[5];
    const float* b2   = (const float*)d_in[6];
    float* out = (float*)d_out;
    float* ws  = (float*)d_ws;

    float* y     = ws + WS_Y;
    float* wgt   = ws + WS_WGT;
    float* bias2 = ws + WS_BIAS2;
    unsigned short* w1b = (unsigned short*)(ws + WS_W1B);
    unsigned short* w2b = (unsigned short*)(ws + WS_W2B);
    unsigned short* xp  = (unsigned short*)(ws + WS_XP);

    mean_kernel <<<dim3(BB * CC / 4), dim3(256), 0, stream>>>(x, y);
    pack_kernel <<<dim3(HWN / 256, CC / 32, BB), dim3(256), 0, stream>>>(x, xp);
    route_kernel<<<dim3(1),           dim3(64),  0, stream>>>(y, fc_w, fc_b, wgt);
    prep_kernel <<<dim3(128),         dim3(256), 0, stream>>>(w1, w2, b2, wgt, w1b, w2b, bias2);
    main_kernel <<<dim3(HWN / NPIX, BB), dim3(512), 0, stream>>>(x, xp, w1b, b1, w2b, wgt, bias2, out);
}

// Round 7
// 303.129 us; speedup vs baseline: 1.1075x; 1.1075x over previous
//
#include <hip/hip_runtime.h>
#include <hip/hip_bf16.h>
#include <math.h>

#define BB 16
#define CC 512
#define HWN 4096
#define KK 4
#define DD 32
#define KD 128
#define NPIX 32

typedef __attribute__((ext_vector_type(8))) short short8;
typedef __attribute__((ext_vector_type(4))) float f32x4;

// ws float offsets
#define WS_Y     0         // [B*C]            8192 f
#define WS_WGT   8192      // [B*K]            64 f
#define WS_BIAS2 8256      // [B*C]            8192 f
#define WS_W1B   16448     // 65536 ushort  = 32768 f
#define WS_W2B   49216     // 65536 ushort  = 32768 f

#define PBASE 32768        // LDS byte offset of partial/hid region

__device__ inline unsigned short f2bf(float f) {
    unsigned u = __builtin_bit_cast(unsigned, f);
    unsigned r = (u + 0x7FFFu + ((u >> 16) & 1u)) >> 16;
    return (unsigned short)r;
}
__device__ inline float bf2f(unsigned short h) {
    unsigned u = (unsigned)h << 16;
    return __builtin_bit_cast(float, u);
}

// ---------------- kernel 1: y[b,c] = mean_{hw} x[b,c,hw] ----------------
__global__ __launch_bounds__(256) void mean_kernel(const float* __restrict__ x,
                                                   float* __restrict__ y) {
    int wave = threadIdx.x >> 6;
    int lane = threadIdx.x & 63;
    int row  = blockIdx.x * 4 + wave;
    const float4* xr = (const float4*)(x + (size_t)row * HWN);
    float s = 0.f;
    #pragma unroll
    for (int i = 0; i < 16; i++) {
        float4 v = xr[i * 64 + lane];
        s += (v.x + v.y) + (v.z + v.w);
    }
    #pragma unroll
    for (int off = 32; off > 0; off >>= 1)
        s += __shfl_down(s, off, 64);
    if (lane == 0) y[row] = s * (1.0f / HWN);
}

// ---------------- kernel 2: routing softmax -> wgt[b,k] ----------------
__global__ __launch_bounds__(64) void route_kernel(const float* __restrict__ y,
                                                   const float* __restrict__ fc_w,
                                                   const float* __restrict__ fc_b,
                                                   float* __restrict__ wgt) {
    __shared__ float logits[BB][KK];
    int t = threadIdx.x;
    int b = t >> 2, k = t & 3;
    const float4* y4 = (const float4*)(y + b * CC);
    const float4* f4 = (const float4*)(fc_w + k * CC);
    float s = fc_b[k];
    for (int i = 0; i < CC / 4; i++) {
        float4 a = y4[i], w = f4[i];
        s += a.x * w.x + a.y * w.y + a.z * w.z + a.w * w.w;
    }
    logits[b][k] = s;
    __syncthreads();
    if (k == 0) {
        float m = logits[b][0];
        #pragma unroll
        for (int j = 1; j < KK; j++) m = fmaxf(m, logits[b][j]);
        float e[KK], sum = 0.f;
        #pragma unroll
        for (int j = 0; j < KK; j++) { e[j] = __expf(logits[b][j] - m); sum += e[j]; }
        float inv = 1.f / sum;
        #pragma unroll
        for (int j = 0; j < KK; j++) wgt[b * KK + j] = e[j] * inv;
    }
}

// ---- kernel 3: pack W1/W2t into MFMA-fragment-ordered bf16; bias2 ----
__global__ __launch_bounds__(256) void prep_kernel(const float* __restrict__ w1,
                                                   const float* __restrict__ w2,
                                                   const float* __restrict__ b2,
                                                   const float* __restrict__ wgt,
                                                   unsigned short* __restrict__ w1b,
                                                   unsigned short* __restrict__ w2b,
                                                   float* __restrict__ bias2) {
    int tid = blockIdx.x * 256 + threadIdx.x;
    int n   = gridDim.x * 256;
    for (int idx = tid; idx < CC * KD; idx += n) {
        int f = idx >> 9, rem = idx & 511;
        int l = rem >> 3, i = rem & 7;
        int ks = f >> 3, m = f & 7;
        int kd = m * 16 + (l & 15);
        int c  = ks * 32 + (l >> 4) * 8 + i;
        w1b[idx] = f2bf(w1[kd * CC + c]);            // w1 is [KD][C]
    }
    for (int idx = tid; idx < CC * KD; idx += n) {
        int f = idx >> 9, rem = idx & 511;
        int l = rem >> 3, i = rem & 7;
        int mc = f >> 2, kk = f & 3;
        int c = mc * 16 + (l & 15);
        int d = (l >> 4) * 8 + i;
        w2b[idx] = f2bf(w2[(kk * CC + c) * DD + d]); // w2 is [K][C][D]
    }
    for (int idx = tid; idx < BB * CC; idx += n) {
        int bb = idx >> 9, c = idx & 511;
        float s = 0.f;
        #pragma unroll
        for (int k = 0; k < KK; k++) s += wgt[bb * KK + k] * b2[k * CC + c];
        bias2[idx] = s;
    }
}

// ------- kernel 4: fused MFMA MLP, single x pass through LDS -------
// grid (HW/32, B), block 256 = 4 waves. Phase A: stage 32pix x 512c x tile
// to LDS as bf16 ([pix][c] rows, XOR-swizzled). Wave wv: pg = wv&1 (16-pix
// group), kh = wv>>1 (C-half). GEMM1 B-frags from LDS; kh=1 publishes fp32
// partials; kh=0 reduces -> hid bf16. GEMM2: 128 channels/wave; epilogue
// multiplies bf16 x from LDS (no second global x read).
__global__ __launch_bounds__(256, 3) void main_kernel(const float* __restrict__ x,
                                                      const unsigned short* __restrict__ w1b,
                                                      const float* __restrict__ b1,
                                                      const unsigned short* __restrict__ w2b,
                                                      const float* __restrict__ wgt,
                                                      const float* __restrict__ bias2,
                                                      float* __restrict__ out) {
    __shared__ char lds[49152];   // [0,32K): x tile bf16; [32K,48K): partials/hid

    const int b       = blockIdx.y;
    const int pixbase = blockIdx.x * NPIX;
    const int tid = threadIdx.x;
    const int wv  = tid >> 6;
    const int l   = tid & 63;
    const int l15 = l & 15, lg = l >> 4;
    const int pg  = wv & 1;
    const int kh  = wv >> 1;

    const short8* w1f = (const short8*)w1b;
    const short8* w2f = (const short8*)w2b;

    // ===== Phase A: stage x tile (32 pix x 512 c) -> LDS bf16 =====
    {
        const int apix = tid & 31;          // pixel within tile
        const int ag   = tid >> 5;          // c-group 0..7
        const float* xb = x + (size_t)b * CC * HWN + pixbase + apix;
        float v[8][8];
        #pragma unroll
        for (int i = 0; i < 8; i++) {
            const int cb = i * 64 + ag * 8;
            #pragma unroll
            for (int j = 0; j < 8; j++)
                v[i][j] = xb[(size_t)(cb + j) * HWN];
        }
        const int sw = (apix & 15) << 4;
        #pragma unroll
        for (int i = 0; i < 8; i++) {
            const int cb = i * 64 + ag * 8;
            uint4 p;
            p.x = (unsigned)f2bf(v[i][0]) | ((unsigned)f2bf(v[i][1]) << 16);
            p.y = (unsigned)f2bf(v[i][2]) | ((unsigned)f2bf(v[i][3]) << 16);
            p.z = (unsigned)f2bf(v[i][4]) | ((unsigned)f2bf(v[i][5]) << 16);
            p.w = (unsigned)f2bf(v[i][6]) | ((unsigned)f2bf(v[i][7]) << 16);
            *(uint4*)(lds + apix * 1024 + ((cb * 2) ^ sw)) = p;
        }
    }
    __syncthreads();

    // ===== GEMM1 partial: ks in [kh*8, kh*8+8), B-frags from LDS =====
    f32x4 acc1[8];
    #pragma unroll
    for (int m = 0; m < 8; m++) acc1[m] = (f32x4)0.f;

    {
        const int mp  = pg * 16 + l15;            // pixel row in tile
        const int msw = (mp & 15) << 4;
        short8 bfr[8];
        #pragma unroll
        for (int ks8 = 0; ks8 < 8; ks8++) {
            const int c0 = (kh * 8 + ks8) * 32 + lg * 8;
            bfr[ks8] = *(const short8*)(lds + mp * 1024 + ((c0 * 2) ^ msw));
        }
        #pragma unroll
        for (int ks8 = 0; ks8 < 8; ks8++) {
            const int ks = kh * 8 + ks8;
            #pragma unroll
            for (int m = 0; m < 8; m++) {
                short8 af = w1f[(ks * 8 + m) * 64 + l];
                acc1[m] = __builtin_amdgcn_mfma_f32_16x16x32_bf16(af, bfr[ks8], acc1[m], 0, 0, 0);
            }
        }
    }

    // ===== upper waves publish fp32 partials =====
    if (kh == 1) {
        char* base = lds + PBASE + pg * 8192 + lg * 256 + l15 * 16;
        #pragma unroll
        for (int m = 0; m < 8; m++)
            *(f32x4*)(base + m * 1024) = acc1[m];
    }
    __syncthreads();

    // ===== lower waves: reduce + relu + bias + wgt -> bf16 hid =====
    if (kh == 0) {
        const char* pbase = lds + PBASE + pg * 8192 + lg * 256 + l15 * 16;
        #pragma unroll
        for (int half = 0; half < 2; half++) {
            f32x4 pp[4];
            #pragma unroll
            for (int m4 = 0; m4 < 4; m4++)
                pp[m4] = *(const f32x4*)(pbase + (half * 4 + m4) * 1024);
            #pragma unroll
            for (int m4 = 0; m4 < 4; m4++) {
                const int m = half * 4 + m4;
                f32x4 bv = *(const f32x4*)(b1 + m * 16 + lg * 4);
                float wk = wgt[b * KK + (m >> 1)];
                f32x4 s = acc1[m] + pp[m4];
                unsigned short h[4];
                #pragma unroll
                for (int r = 0; r < 4; r++) {
                    float t = fmaxf(s[r] + bv[r], 0.f) * wk;
                    h[r] = f2bf(t);
                }
                unsigned lo = (unsigned)h[0] | ((unsigned)h[1] << 16);
                unsigned hi = (unsigned)h[2] | ((unsigned)h[3] << 16);
                int byteoff = PBASE + pg * 8192 + l15 * 256 + (((m * 16 + lg * 4) * 2) ^ ((l15 & 7) << 4));
                uint2 v; v.x = lo; v.y = hi;
                *(uint2*)(lds + byteoff) = v;
            }
        }
    }
    __syncthreads();

    // ===== GEMM2: 128 channels/wave; epilogue from LDS bf16 x =====
    short8 breg[4][2];
    #pragma unroll
    for (int kk = 0; kk < 4; kk++)
        #pragma unroll
        for (int nb = 0; nb < 2; nb++)
            breg[kk][nb] = *(const short8*)(lds + PBASE + nb * 8192 + l15 * 256 +
                                            (((kk * 64 + lg * 16)) ^ ((l15 & 7) << 4)));

    const float* bb2 = bias2 + b * CC;
    #pragma unroll
    for (int mblk = 0; mblk < 8; mblk++) {
        f32x4 acc[2];
        acc[0] = (f32x4)0.f; acc[1] = (f32x4)0.f;
        #pragma unroll
        for (int kk = 0; kk < 4; kk++) {
            short8 af = w2f[((wv * 8 + mblk) * 4 + kk) * 64 + l];
            #pragma unroll
            for (int nb = 0; nb < 2; nb++)
                acc[nb] = __builtin_amdgcn_mfma_f32_16x16x32_bf16(af, breg[kk][nb], acc[nb], 0, 0, 0);
        }
        const int cb = wv * 128 + mblk * 16 + lg * 4;
        f32x4 b2v = *(const f32x4*)(bb2 + cb);
        #pragma unroll
        for (int nb = 0; nb < 2; nb++) {
            const int pixl = nb * 16 + l15;
            uint2 xw = *(const uint2*)(lds + pixl * 1024 + ((cb * 2) ^ ((pixl & 15) << 4)));
            float xr[4];
            xr[0] = bf2f((unsigned short)(xw.x & 0xFFFF));
            xr[1] = bf2f((unsigned short)(xw.x >> 16));
            xr[2] = bf2f((unsigned short)(xw.y & 0xFFFF));
            xr[3] = bf2f((unsigned short)(xw.y >> 16));
            const int pix = pixbase + pixl;
            #pragma unroll
            for (int r = 0; r < 4; r++) {
                size_t off = ((size_t)b * CC + cb + r) * HWN + pix;
                float s = acc[nb][r] + b2v[r];
                float attn = __builtin_amdgcn_rcpf(1.f + __expf(-s));
                __builtin_nontemporal_store(xr[r] * attn, &out[off]);
            }
        }
    }
}

extern "C" void kernel_launch(void* const* d_in, const int* in_sizes, int n_in,
                              void* d_out, int out_size, void* d_ws, size_t ws_size,
                              hipStream_t stream) {
    const float* x    = (const float*)d_in[0];
    const float* fc_w = (const float*)d_in[1];
    const float* fc_b = (const float*)d_in[2];
    const float* w1   = (const float*)d_in[3];
    const float* b1   = (const float*)d_in[4];
    const float* w2   = (const float*)d_in[5];
    const float* b2   = (const float*)d_in[6];
    float* out = (float*)d_out;
    float* ws  = (float*)d_ws;

    float* y     = ws + WS_Y;
    float* wgt   = ws + WS_WGT;
    float* bias2 = ws + WS_BIAS2;
    unsigned short* w1b = (unsigned short*)(ws + WS_W1B);
    unsigned short* w2b = (unsigned short*)(ws + WS_W2B);

    mean_kernel <<<dim3(BB * CC / 4), dim3(256), 0, stream>>>(x, y);
    route_kernel<<<dim3(1),           dim3(64),  0, stream>>>(y, fc_w, fc_b, wgt);
    prep_kernel <<<dim3(128),         dim3(256), 0, stream>>>(w1, w2, b2, wgt, w1b, w2b, bias2);
    main_kernel <<<dim3(HWN / NPIX, BB), dim3(256), 0, stream>>>(x, w1b, b1, w2b, wgt, bias2, out);
}